// Round 6
// baseline (1084.128 us; speedup 1.0000x reference)
//
#include <hip/hip_runtime.h>

// PairwiseMLPLinkPredictor on MI355X (gfx950)
// feats = bf16(x[u]) * bf16(x[v]);  h1 = relu(feats@W1+b1);  h2 = relu(h1@W2+b2);
// out = h2@W3 + b3.
//
// R10: restore TLP -- 2 blocks/CU (from R9 @ 310us: latency-bound at 2 waves/SIMD;
// DS pipe ~60%, nothing else >33%; ILP-within-wave insufficient).
//  - feats and h1 SINGLE-buffered: LDS 66.5KB/block -> 2 blocks/CU -> 4 waves/SIMD.
//    Cross-block TLP covers the 3-barrier/tile serialization (R4b precedent: same
//    barrier count at 45% occupancy).
//  - NBLOCKS=512 persistent (2 per CU), NTHREADS=512, __launch_bounds__(512,4):
//    VGPR cap 128 = exactly 2 blocks' worth (2*512*128 = 131072 = CU file).
//  - all verified per-tile wins kept: 32-col waves (R8), packed b32 h1 writeback
//    + w2t k-perm (R8), part[]+coalesced store (R5), gathers/ep issued at iter
//    top with full-tile latency cover (R9).
// Barrier schedule per iter i (tile t = b + i*NBLOCKS):
//   [gathers(i+1), uv(i+2)] GEMM2(i-1)->part | bar1 | store(i-1), GEMM1(i)->h1
//   | bar2 | stage feats(i+1) | bar3

typedef __attribute__((ext_vector_type(8))) short short8;   // 8 bf16 = 4 VGPRs
typedef __attribute__((ext_vector_type(4))) float floatx4;  // MFMA C/D frag
typedef __attribute__((ext_vector_type(4))) unsigned uintx4;
typedef __attribute__((ext_vector_type(2))) int intx2;

#define MT 64         // pairs per tile
#define NTHREADS 512  // 8 waves
#define NBLOCKS 512   // persistent, 2 blocks/CU

__device__ __forceinline__ unsigned short f2bf(float f) {
  union { float f; unsigned u; } a; a.f = f;
  unsigned r = a.u + 0x7FFFu + ((a.u >> 16) & 1u);   // RNE
  return (unsigned short)(r >> 16);
}

// hw packed f32x2 -> bf16x2 (RNE), lo in low 16
__device__ __forceinline__ unsigned pkbf(float lo, float hi) {
  unsigned r;
  asm("v_cvt_pk_bf16_f32 %0, %1, %2" : "=v"(r) : "v"(lo), "v"(hi));
  return r;
}

// packed bf16x2 multiply via f32 unpack + hw repack
__device__ __forceinline__ unsigned bfmul2(unsigned ua, unsigned ub) {
  float lo = __uint_as_float(ua << 16)          * __uint_as_float(ub << 16);
  float hi = __uint_as_float(ua & 0xFFFF0000u) * __uint_as_float(ub & 0xFFFF0000u);
  return pkbf(lo, hi);
}

// ---------- prologue: x -> bf16 table; W1/W2 -> bf16 transposed [n][k] ----------
// w2t's k-dimension is stored PERMUTED: storage index p holds logical k
// kperm(p) = (p & ~31) | ((p&1)<<4) | ((p&31)>>1), matching the h1 writeback
// packing (lane packs cols n1, n1+16 into adjacent storage slots 2*r16, 2*r16+1).
__global__ void prep_kernel(const float* __restrict__ x,
                            const float* __restrict__ W1,
                            const float* __restrict__ W2,
                            unsigned short* __restrict__ xb,
                            unsigned short* __restrict__ w1t,
                            unsigned short* __restrict__ w2t, int n4) {
  int i = blockIdx.x * blockDim.x + threadIdx.x;
  if (i < n4) {
    float4 v = ((const float4*)x)[i];
    ushort4 o;
    o.x = f2bf(v.x); o.y = f2bf(v.y); o.z = f2bf(v.z); o.w = f2bf(v.w);
    ((ushort4*)xb)[i] = o;
  } else {
    int j = i - n4;
    if (j < 256 * 256) {
      int k = j >> 8, n = j & 255;
      w1t[n * 256 + k] = f2bf(W1[k * 256 + n]);
    } else {
      j -= 256 * 256;
      if (j < 128 * 256) {
        int p = j >> 7, n = j & 127;                       // p = storage k-index
        int kp = (p & ~31) | ((p & 1) << 4) | ((p & 31) >> 1);
        w2t[n * 256 + p] = f2bf(W2[kp * 128 + n]);
      }
    }
  }
}

// ---------- fused pairwise MLP, persistent, 8 waves, 2 blocks/CU ----------
__global__ __launch_bounds__(NTHREADS, 4) void mlp_kernel(
    const unsigned short* __restrict__ xb,
    const unsigned short* __restrict__ w1t,
    const unsigned short* __restrict__ w2t,
    const float* __restrict__ b1,
    const float* __restrict__ b2,
    const float* __restrict__ w3,
    const float* __restrict__ b3,
    const int* __restrict__ ep,
    float* __restrict__ out,
    int E)
{
  // 16B chunks XOR-swizzled by (row & 15): conflict-free stride-512 ds_read_b128.
  // SINGLE-buffered: 32K + 32K + 1K = 66.5KB -> 2 blocks/CU.
  __shared__ __align__(16) unsigned short feats[MT * 256]; // 32 KB
  __shared__ __align__(16) unsigned short h1b[MT * 256];   // 32 KB
  __shared__ __align__(16) float part[MT][4];              // 1 KB

  const int tid  = threadIdx.x;
  const int wv   = tid >> 6;      // 0..7
  const int lane = tid & 63;
  const int q    = lane >> 4;     // quad 0..3
  const int r16  = lane & 15;
  const int c    = tid & 31;      // 16B chunk within 512B row (staging)
  const int mrow = tid >> 5;      // staging row base 0..15 (rows mrow + 16s)
  const int mg   = wv >> 2;       // GEMM2 row slab 0..1
  const int cg   = wv & 3;        // GEMM2 col group 0..3

  const int ntiles = (E + MT - 1) / MT;        // 15625 (E = 64*15625 exactly)
  const int b = blockIdx.x;
  const int nloc = (ntiles - 1 - b) / NBLOCKS + 1;   // ~30-31 tiles/block

  // ---- weights: W1 2ct x 8kt + W2 2ct x 8kt (compiler keeps what fits in 128) ----
  short8 w1r[2][8], w2r[2][8];
  float b1r[2], b2r[2], w3r[2];
  #pragma unroll
  for (int ct = 0; ct < 2; ++ct) {
    const int n1 = wv * 32 + ct * 16 + r16;            // W1 col 0..255
    const unsigned short* p1 = w1t + n1 * 256 + q * 8;
    #pragma unroll
    for (int kt = 0; kt < 8; ++kt) w1r[ct][kt] = *(const short8*)(p1 + kt * 32);
    b1r[ct] = b1[n1];
    const int n2 = cg * 32 + ct * 16 + r16;            // W2 col 0..127
    const unsigned short* p2 = w2t + n2 * 256 + q * 8;
    #pragma unroll
    for (int kt = 0; kt < 8; ++kt) w2r[ct][kt] = *(const short8*)(p2 + kt * 32);
    b2r[ct] = b2[n2];
    w3r[ct] = w3[n2];
  }
  const float b3v = b3[0];

  // ---- prologue: stage tile 0 into feats; load uv for tile 1 ----
  intx2 uv0, uv1, uv2, uv3;
  {
    #pragma unroll
    for (int s = 0; s < 4; ++s) {
      int m = mrow + 16 * s;
      int g = b * MT + m;                       // < 512*64 << E, no clamp needed
      intx2 uv = __builtin_nontemporal_load((const intx2*)(ep + 2 * (size_t)g));
      uintx4 a  = *(const uintx4*)(xb + ((size_t)(unsigned)uv.x << 8) + (c << 3));
      uintx4 bv = *(const uintx4*)(xb + ((size_t)(unsigned)uv.y << 8) + (c << 3));
      uintx4 pv;
      #pragma unroll
      for (int tt = 0; tt < 4; ++tt) pv[tt] = bfmul2(a[tt], bv[tt]);
      *(uintx4*)((char*)feats + m * 512 + ((c ^ (m & 15)) << 4)) = pv;
    }
    const int t1 = b + NBLOCKS;                 // local tile 1 (nloc >= 2 always)
    uv0 = __builtin_nontemporal_load((const intx2*)(ep + 2 * (size_t)(t1 * MT + mrow)));
    uv1 = __builtin_nontemporal_load((const intx2*)(ep + 2 * (size_t)(t1 * MT + mrow + 16)));
    uv2 = __builtin_nontemporal_load((const intx2*)(ep + 2 * (size_t)(t1 * MT + mrow + 32)));
    uv3 = __builtin_nontemporal_load((const intx2*)(ep + 2 * (size_t)(t1 * MT + mrow + 48)));
  }
  __syncthreads();

  for (int i = 0; i <= nloc; ++i) {
    const bool stg = (i + 1 < nloc);   // stage tile i+1 this iteration

    // ---- (0) issue gathers(i+1) + prefetch uv(i+2): full-tile latency cover ----
    uintx4 ra0, rb0, ra1, rb1, ra2, rb2, ra3, rb3;
    if (stg) {
      ra0 = *(const uintx4*)(xb + ((size_t)(unsigned)uv0.x << 8) + (c << 3));
      rb0 = *(const uintx4*)(xb + ((size_t)(unsigned)uv0.y << 8) + (c << 3));
      ra1 = *(const uintx4*)(xb + ((size_t)(unsigned)uv1.x << 8) + (c << 3));
      rb1 = *(const uintx4*)(xb + ((size_t)(unsigned)uv1.y << 8) + (c << 3));
      ra2 = *(const uintx4*)(xb + ((size_t)(unsigned)uv2.x << 8) + (c << 3));
      rb2 = *(const uintx4*)(xb + ((size_t)(unsigned)uv2.y << 8) + (c << 3));
      ra3 = *(const uintx4*)(xb + ((size_t)(unsigned)uv3.x << 8) + (c << 3));
      rb3 = *(const uintx4*)(xb + ((size_t)(unsigned)uv3.y << 8) + (c << 3));

      const int t2 = b + (i + 2) * NBLOCKS;
      int g0 = t2 * MT + mrow;      if (g0 >= E) g0 = E - 1;
      int g1 = t2 * MT + mrow + 16; if (g1 >= E) g1 = E - 1;
      int g2 = t2 * MT + mrow + 32; if (g2 >= E) g2 = E - 1;
      int g3 = t2 * MT + mrow + 48; if (g3 >= E) g3 = E - 1;
      uv0 = __builtin_nontemporal_load((const intx2*)(ep + 2 * (size_t)g0));
      uv1 = __builtin_nontemporal_load((const intx2*)(ep + 2 * (size_t)g1));
      uv2 = __builtin_nontemporal_load((const intx2*)(ep + 2 * (size_t)g2));
      uv3 = __builtin_nontemporal_load((const intx2*)(ep + 2 * (size_t)g3));
    }

    // ---- (1) GEMM2 tile i-1: h1b x w2r (k in permuted order) -> part ----
    if (i >= 1) {
      floatx4 acc2[2][2];
      acc2[0][0] = (floatx4){0.f, 0.f, 0.f, 0.f};
      acc2[0][1] = (floatx4){0.f, 0.f, 0.f, 0.f};
      acc2[1][0] = (floatx4){0.f, 0.f, 0.f, 0.f};
      acc2[1][1] = (floatx4){0.f, 0.f, 0.f, 0.f};
      const char* const a2base = (const char*)h1b + (mg * 32 + r16) * 512;
      #pragma unroll
      for (int kt = 0; kt < 8; ++kt) {
        const int aoff = (kt << 6) ^ ((q ^ r16) << 4);
        short8 av0 = *(const short8*)(a2base + aoff);
        short8 av1 = *(const short8*)(a2base + 16 * 512 + aoff);
        acc2[0][0] = __builtin_amdgcn_mfma_f32_16x16x32_bf16(av0, w2r[0][kt], acc2[0][0], 0, 0, 0);
        acc2[0][1] = __builtin_amdgcn_mfma_f32_16x16x32_bf16(av0, w2r[1][kt], acc2[0][1], 0, 0, 0);
        acc2[1][0] = __builtin_amdgcn_mfma_f32_16x16x32_bf16(av1, w2r[0][kt], acc2[1][0], 0, 0, 0);
        acc2[1][1] = __builtin_amdgcn_mfma_f32_16x16x32_bf16(av1, w2r[1][kt], acc2[1][1], 0, 0, 0);
      }
      // layer 3 partials: relu(h2)*w3, reduce over r16, part[m][cg]
      #pragma unroll
      for (int mt = 0; mt < 2; ++mt) {
        #pragma unroll
        for (int r = 0; r < 4; ++r) {
          float pp = fmaxf(acc2[mt][0][r] + b2r[0], 0.f) * w3r[0]
                   + fmaxf(acc2[mt][1][r] + b2r[1], 0.f) * w3r[1];
          pp += __shfl_xor(pp, 1);
          pp += __shfl_xor(pp, 2);
          pp += __shfl_xor(pp, 4);
          pp += __shfl_xor(pp, 8);
          if (r16 == 0)
            part[mg * 32 + mt * 16 + q * 4 + r][cg] = pp;
        }
      }
    }
    __syncthreads();   // bar1: part ready; h1b free for GEMM1(i) writes

    // ---- (2) store out(i-1) (wave 0 only; others fall through to GEMM1) ----
    if (i >= 1 && tid < MT) {
      floatx4 pr = *(const floatx4*)part[tid];
      out[(size_t)(b + (i - 1) * NBLOCKS) * MT + tid] =
          (pr[0] + pr[1]) + (pr[2] + pr[3]) + b3v;
    }

    // ---- (3) GEMM1 tile i: feats x w1r, two 32-row halves -> h1b ----
    if (i < nloc) {
      char* const hb = (char*)h1b;
      const int chp = wv * 4 + (r16 >> 2);
      const int ino = (r16 & 3) << 2;
      #pragma unroll
      for (int mh = 0; mh < 2; ++mh) {
        floatx4 acc[2][2];
        #pragma unroll
        for (int mt = 0; mt < 2; ++mt) {
          acc[mt][0] = (floatx4){0.f, 0.f, 0.f, 0.f};
          acc[mt][1] = (floatx4){0.f, 0.f, 0.f, 0.f};
        }
        const char* const a1base =
            (const char*)feats + r16 * 512 + mh * (32 * 512);
        #pragma unroll
        for (int kt = 0; kt < 8; ++kt) {
          const int aoff = (kt << 6) ^ ((q ^ r16) << 4);
          #pragma unroll
          for (int mt = 0; mt < 2; ++mt) {
            short8 av = *(const short8*)(a1base + mt * (16 * 512) + aoff);
            acc[mt][0] = __builtin_amdgcn_mfma_f32_16x16x32_bf16(av, w1r[0][kt], acc[mt][0], 0, 0, 0);
            acc[mt][1] = __builtin_amdgcn_mfma_f32_16x16x32_bf16(av, w1r[1][kt], acc[mt][1], 0, 0, 0);
          }
        }
        // h1 writeback: pack (ct0,ct1) -> one b32 store per (mt,r)
        #pragma unroll
        for (int mt = 0; mt < 2; ++mt) {
          #pragma unroll
          for (int r = 0; r < 4; ++r) {
            const int m = mh * 32 + mt * 16 + q * 4 + r;
            unsigned pk = pkbf(fmaxf(acc[mt][0][r] + b1r[0], 0.f),
                               fmaxf(acc[mt][1][r] + b1r[1], 0.f));
            *(unsigned*)(hb + m * 512 + ((chp ^ (m & 15)) << 4) + ino) = pk;
          }
        }
      }
    }
    __syncthreads();   // bar2: feats reads done -> staging may overwrite

    // ---- (4) stage feats(i+1) from pre-issued gathers ----
    if (stg) {
      char* const bufn = (char*)feats;
      uintx4 pv;
      int m = mrow;
      #pragma unroll
      for (int tt = 0; tt < 4; ++tt) pv[tt] = bfmul2(ra0[tt], rb0[tt]);
      *(uintx4*)(bufn + m * 512 + ((c ^ (m & 15)) << 4)) = pv;
      m = mrow + 16;
      #pragma unroll
      for (int tt = 0; tt < 4; ++tt) pv[tt] = bfmul2(ra1[tt], rb1[tt]);
      *(uintx4*)(bufn + m * 512 + ((c ^ (m & 15)) << 4)) = pv;
      m = mrow + 32;
      #pragma unroll
      for (int tt = 0; tt < 4; ++tt) pv[tt] = bfmul2(ra2[tt], rb2[tt]);
      *(uintx4*)(bufn + m * 512 + ((c ^ (m & 15)) << 4)) = pv;
      m = mrow + 48;
      #pragma unroll
      for (int tt = 0; tt < 4; ++tt) pv[tt] = bfmul2(ra3[tt], rb3[tt]);
      *(uintx4*)(bufn + m * 512 + ((c ^ (m & 15)) << 4)) = pv;
    }
    __syncthreads();   // bar3: feats(i+1) ready; h1(i) ready for GEMM2 next iter
  }
}

extern "C" void kernel_launch(void* const* d_in, const int* in_sizes, int n_in,
                              void* d_out, int out_size, void* d_ws, size_t ws_size,
                              hipStream_t stream) {
  const float* x  = (const float*)d_in[0];
  const float* W1 = (const float*)d_in[1];
  const float* b1 = (const float*)d_in[2];
  const float* W2 = (const float*)d_in[3];
  const float* b2 = (const float*)d_in[4];
  const float* W3 = (const float*)d_in[5];
  const float* b3 = (const float*)d_in[6];
  // d_in[7] = edge_index (unused by the reference computation)
  const int*   ep = (const int*)d_in[8];
  float* out = (float*)d_out;

  const int NX = in_sizes[0];        // 100000*256 = 25,600,000
  const int E  = in_sizes[8] / 2;    // 1,000,000

  // workspace layout: xb (NX bf16) | w1t (256*256 bf16) | w2t (128*256 bf16)
  unsigned short* xb  = (unsigned short*)d_ws;
  unsigned short* w1t = (unsigned short*)((char*)d_ws + (size_t)NX * 2);
  unsigned short* w2t = w1t + 256 * 256;

  const int n4 = NX / 4;
  const int prep_threads = n4 + 256 * 256 + 128 * 256;
  prep_kernel<<<(prep_threads + 255) / 256, 256, 0, stream>>>(x, W1, W2, xb, w1t, w2t, n4);
  mlp_kernel<<<NBLOCKS, NTHREADS, 0, stream>>>(xb, w1t, w2t, b1, b2, W3, b3, ep, out, E);
}

// Round 8
// 478.758 us; speedup vs baseline: 2.2645x; 2.2645x over previous
//
#include <hip/hip_runtime.h>

// PairwiseMLPLinkPredictor on MI355X (gfx950)
// feats = bf16(x[u]) * bf16(x[v]);  h1 = relu(feats@W1+b1);  h2 = relu(h1@W2+b2);
// out = h2@W3 + b3.
//
// R12: R10 EXACT structure + launch_bounds (512,4)->(512,2). Single-variable
// experiment after R11's nondeterministic post-timing divergence (R11 changed
// TWO things vs passed-R10: launch bounds AND gather placement; this round
// reverts the gather placement to R10's verified ordering).
//
// Occupancy model (now consistent across R5-R11):
//   VGPR budget = 512/SIMD / min(8, ceil(min_blocks*waves_per_block/4))
//   (1024,4)->64 ; (512,2)->128 ; (512,4)->64+spill(R10 catastrophe).
//   2nd arg is CUDA-style MIN BLOCKS/CU on this toolchain.
// (512,2): 128-reg budget, 2 blocks co-resident (66.5KB LDS, R10 measured 43.5%
// occupancy) -> TLP 4 waves/SIMD + near-resident weights (R9: graceful, 0 spill).

typedef __attribute__((ext_vector_type(8))) short short8;   // 8 bf16 = 4 VGPRs
typedef __attribute__((ext_vector_type(4))) float floatx4;  // MFMA C/D frag
typedef __attribute__((ext_vector_type(4))) unsigned uintx4;
typedef __attribute__((ext_vector_type(2))) int intx2;

#define MT 64         // pairs per tile
#define NTHREADS 512  // 8 waves
#define NBLOCKS 512   // persistent, 2 blocks/CU

__device__ __forceinline__ unsigned short f2bf(float f) {
  union { float f; unsigned u; } a; a.f = f;
  unsigned r = a.u + 0x7FFFu + ((a.u >> 16) & 1u);   // RNE
  return (unsigned short)(r >> 16);
}

// hw packed f32x2 -> bf16x2 (RNE), lo in low 16
__device__ __forceinline__ unsigned pkbf(float lo, float hi) {
  unsigned r;
  asm("v_cvt_pk_bf16_f32 %0, %1, %2" : "=v"(r) : "v"(lo), "v"(hi));
  return r;
}

// packed bf16x2 multiply via f32 unpack + hw repack
__device__ __forceinline__ unsigned bfmul2(unsigned ua, unsigned ub) {
  float lo = __uint_as_float(ua << 16)          * __uint_as_float(ub << 16);
  float hi = __uint_as_float(ua & 0xFFFF0000u) * __uint_as_float(ub & 0xFFFF0000u);
  return pkbf(lo, hi);
}

// ---------- prologue: x -> bf16 table; W1/W2 -> bf16 transposed [n][k] ----------
// w2t's k-dimension is stored PERMUTED: storage index p holds logical k
// kperm(p) = (p & ~31) | ((p&1)<<4) | ((p&31)>>1), matching the h1 writeback
// packing (lane packs cols n1, n1+16 into adjacent storage slots 2*r16, 2*r16+1).
__global__ void prep_kernel(const float* __restrict__ x,
                            const float* __restrict__ W1,
                            const float* __restrict__ W2,
                            unsigned short* __restrict__ xb,
                            unsigned short* __restrict__ w1t,
                            unsigned short* __restrict__ w2t, int n4) {
  int i = blockIdx.x * blockDim.x + threadIdx.x;
  if (i < n4) {
    float4 v = ((const float4*)x)[i];
    ushort4 o;
    o.x = f2bf(v.x); o.y = f2bf(v.y); o.z = f2bf(v.z); o.w = f2bf(v.w);
    ((ushort4*)xb)[i] = o;
  } else {
    int j = i - n4;
    if (j < 256 * 256) {
      int k = j >> 8, n = j & 255;
      w1t[n * 256 + k] = f2bf(W1[k * 256 + n]);
    } else {
      j -= 256 * 256;
      if (j < 128 * 256) {
        int p = j >> 7, n = j & 127;                       // p = storage k-index
        int kp = (p & ~31) | ((p & 1) << 4) | ((p & 31) >> 1);
        w2t[n * 256 + p] = f2bf(W2[kp * 128 + n]);
      }
    }
  }
}

// ---------- fused pairwise MLP, persistent, 8 waves, 2 blocks/CU ----------
__global__ __launch_bounds__(NTHREADS, 2) void mlp_kernel(
    const unsigned short* __restrict__ xb,
    const unsigned short* __restrict__ w1t,
    const unsigned short* __restrict__ w2t,
    const float* __restrict__ b1,
    const float* __restrict__ b2,
    const float* __restrict__ w3,
    const float* __restrict__ b3,
    const int* __restrict__ ep,
    float* __restrict__ out,
    int E)
{
  // 16B chunks XOR-swizzled by (row & 15): conflict-free stride-512 ds_read_b128.
  // SINGLE-buffered: 32K + 32K + 1K = 66.5KB -> 2 blocks/CU.
  __shared__ __align__(16) unsigned short feats[MT * 256]; // 32 KB
  __shared__ __align__(16) unsigned short h1b[MT * 256];   // 32 KB
  __shared__ __align__(16) float part[MT][4];              // 1 KB

  const int tid  = threadIdx.x;
  const int wv   = tid >> 6;      // 0..7
  const int lane = tid & 63;
  const int q    = lane >> 4;     // quad 0..3
  const int r16  = lane & 15;
  const int c    = tid & 31;      // 16B chunk within 512B row (staging)
  const int mrow = tid >> 5;      // staging row base 0..15 (rows mrow + 16s)
  const int mg   = wv >> 2;       // GEMM2 row slab 0..1
  const int cg   = wv & 3;        // GEMM2 col group 0..3

  const int ntiles = (E + MT - 1) / MT;        // 15625 (E = 64*15625 exactly)
  const int b = blockIdx.x;
  const int nloc = (ntiles - 1 - b) / NBLOCKS + 1;   // ~30-31 tiles/block

  // ---- weights: W1 2ct x 8kt + W2 2ct x 8kt (allocator keeps what fits) ----
  short8 w1r[2][8], w2r[2][8];
  float b1r[2], b2r[2], w3r[2];
  #pragma unroll
  for (int ct = 0; ct < 2; ++ct) {
    const int n1 = wv * 32 + ct * 16 + r16;            // W1 col 0..255
    const unsigned short* p1 = w1t + n1 * 256 + q * 8;
    #pragma unroll
    for (int kt = 0; kt < 8; ++kt) w1r[ct][kt] = *(const short8*)(p1 + kt * 32);
    b1r[ct] = b1[n1];
    const int n2 = cg * 32 + ct * 16 + r16;            // W2 col 0..127
    const unsigned short* p2 = w2t + n2 * 256 + q * 8;
    #pragma unroll
    for (int kt = 0; kt < 8; ++kt) w2r[ct][kt] = *(const short8*)(p2 + kt * 32);
    b2r[ct] = b2[n2];
    w3r[ct] = w3[n2];
  }
  const float b3v = b3[0];

  // ---- prologue: stage tile 0 into feats; load uv for tile 1 ----
  intx2 uv0, uv1, uv2, uv3;
  {
    #pragma unroll
    for (int s = 0; s < 4; ++s) {
      int m = mrow + 16 * s;
      int g = b * MT + m;                       // < 512*64 << E, no clamp needed
      intx2 uv = __builtin_nontemporal_load((const intx2*)(ep + 2 * (size_t)g));
      uintx4 a  = *(const uintx4*)(xb + ((size_t)(unsigned)uv.x << 8) + (c << 3));
      uintx4 bv = *(const uintx4*)(xb + ((size_t)(unsigned)uv.y << 8) + (c << 3));
      uintx4 pv;
      #pragma unroll
      for (int tt = 0; tt < 4; ++tt) pv[tt] = bfmul2(a[tt], bv[tt]);
      *(uintx4*)((char*)feats + m * 512 + ((c ^ (m & 15)) << 4)) = pv;
    }
    const int t1 = b + NBLOCKS;                 // local tile 1 (nloc >= 2 always)
    uv0 = __builtin_nontemporal_load((const intx2*)(ep + 2 * (size_t)(t1 * MT + mrow)));
    uv1 = __builtin_nontemporal_load((const intx2*)(ep + 2 * (size_t)(t1 * MT + mrow + 16)));
    uv2 = __builtin_nontemporal_load((const intx2*)(ep + 2 * (size_t)(t1 * MT + mrow + 32)));
    uv3 = __builtin_nontemporal_load((const intx2*)(ep + 2 * (size_t)(t1 * MT + mrow + 48)));
  }
  __syncthreads();

  for (int i = 0; i <= nloc; ++i) {
    const bool stg = (i + 1 < nloc);   // stage tile i+1 this iteration

    // ---- (0) issue gathers(i+1) + prefetch uv(i+2): full-tile latency cover ----
    uintx4 ra0, rb0, ra1, rb1, ra2, rb2, ra3, rb3;
    if (stg) {
      ra0 = *(const uintx4*)(xb + ((size_t)(unsigned)uv0.x << 8) + (c << 3));
      rb0 = *(const uintx4*)(xb + ((size_t)(unsigned)uv0.y << 8) + (c << 3));
      ra1 = *(const uintx4*)(xb + ((size_t)(unsigned)uv1.x << 8) + (c << 3));
      rb1 = *(const uintx4*)(xb + ((size_t)(unsigned)uv1.y << 8) + (c << 3));
      ra2 = *(const uintx4*)(xb + ((size_t)(unsigned)uv2.x << 8) + (c << 3));
      rb2 = *(const uintx4*)(xb + ((size_t)(unsigned)uv2.y << 8) + (c << 3));
      ra3 = *(const uintx4*)(xb + ((size_t)(unsigned)uv3.x << 8) + (c << 3));
      rb3 = *(const uintx4*)(xb + ((size_t)(unsigned)uv3.y << 8) + (c << 3));

      const int t2 = b + (i + 2) * NBLOCKS;
      int g0 = t2 * MT + mrow;      if (g0 >= E) g0 = E - 1;
      int g1 = t2 * MT + mrow + 16; if (g1 >= E) g1 = E - 1;
      int g2 = t2 * MT + mrow + 32; if (g2 >= E) g2 = E - 1;
      int g3 = t2 * MT + mrow + 48; if (g3 >= E) g3 = E - 1;
      uv0 = __builtin_nontemporal_load((const intx2*)(ep + 2 * (size_t)g0));
      uv1 = __builtin_nontemporal_load((const intx2*)(ep + 2 * (size_t)g1));
      uv2 = __builtin_nontemporal_load((const intx2*)(ep + 2 * (size_t)g2));
      uv3 = __builtin_nontemporal_load((const intx2*)(ep + 2 * (size_t)g3));
    }

    // ---- (1) GEMM2 tile i-1: h1b x w2r (k in permuted order) -> part ----
    if (i >= 1) {
      floatx4 acc2[2][2];
      acc2[0][0] = (floatx4){0.f, 0.f, 0.f, 0.f};
      acc2[0][1] = (floatx4){0.f, 0.f, 0.f, 0.f};
      acc2[1][0] = (floatx4){0.f, 0.f, 0.f, 0.f};
      acc2[1][1] = (floatx4){0.f, 0.f, 0.f, 0.f};
      const char* const a2base = (const char*)h1b + (mg * 32 + r16) * 512;
      #pragma unroll
      for (int kt = 0; kt < 8; ++kt) {
        const int aoff = (kt << 6) ^ ((q ^ r16) << 4);
        short8 av0 = *(const short8*)(a2base + aoff);
        short8 av1 = *(const short8*)(a2base + 16 * 512 + aoff);
        acc2[0][0] = __builtin_amdgcn_mfma_f32_16x16x32_bf16(av0, w2r[0][kt], acc2[0][0], 0, 0, 0);
        acc2[0][1] = __builtin_amdgcn_mfma_f32_16x16x32_bf16(av0, w2r[1][kt], acc2[0][1], 0, 0, 0);
        acc2[1][0] = __builtin_amdgcn_mfma_f32_16x16x32_bf16(av1, w2r[0][kt], acc2[1][0], 0, 0, 0);
        acc2[1][1] = __builtin_amdgcn_mfma_f32_16x16x32_bf16(av1, w2r[1][kt], acc2[1][1], 0, 0, 0);
      }
      // layer 3 partials: relu(h2)*w3, reduce over r16, part[m][cg]
      #pragma unroll
      for (int mt = 0; mt < 2; ++mt) {
        #pragma unroll
        for (int r = 0; r < 4; ++r) {
          float pp = fmaxf(acc2[mt][0][r] + b2r[0], 0.f) * w3r[0]
                   + fmaxf(acc2[mt][1][r] + b2r[1], 0.f) * w3r[1];
          pp += __shfl_xor(pp, 1);
          pp += __shfl_xor(pp, 2);
          pp += __shfl_xor(pp, 4);
          pp += __shfl_xor(pp, 8);
          if (r16 == 0)
            part[mg * 32 + mt * 16 + q * 4 + r][cg] = pp;
        }
      }
    }
    __syncthreads();   // bar1: part ready; h1b free for GEMM1(i) writes

    // ---- (2) store out(i-1) (first 64 lanes; others fall through to GEMM1) ----
    if (i >= 1 && tid < MT) {
      floatx4 pr = *(const floatx4*)part[tid];
      out[(size_t)(b + (i - 1) * NBLOCKS) * MT + tid] =
          (pr[0] + pr[1]) + (pr[2] + pr[3]) + b3v;
    }

    // ---- (3) GEMM1 tile i: feats x w1r, two 32-row halves -> h1b ----
    if (i < nloc) {
      char* const hb = (char*)h1b;
      const int chp = wv * 4 + (r16 >> 2);
      const int ino = (r16 & 3) << 2;
      #pragma unroll
      for (int mh = 0; mh < 2; ++mh) {
        floatx4 acc[2][2];
        #pragma unroll
        for (int mt = 0; mt < 2; ++mt) {
          acc[mt][0] = (floatx4){0.f, 0.f, 0.f, 0.f};
          acc[mt][1] = (floatx4){0.f, 0.f, 0.f, 0.f};
        }
        const char* const a1base =
            (const char*)feats + r16 * 512 + mh * (32 * 512);
        #pragma unroll
        for (int kt = 0; kt < 8; ++kt) {
          const int aoff = (kt << 6) ^ ((q ^ r16) << 4);
          #pragma unroll
          for (int mt = 0; mt < 2; ++mt) {
            short8 av = *(const short8*)(a1base + mt * (16 * 512) + aoff);
            acc[mt][0] = __builtin_amdgcn_mfma_f32_16x16x32_bf16(av, w1r[0][kt], acc[mt][0], 0, 0, 0);
            acc[mt][1] = __builtin_amdgcn_mfma_f32_16x16x32_bf16(av, w1r[1][kt], acc[mt][1], 0, 0, 0);
          }
        }
        // h1 writeback: pack (ct0,ct1) -> one b32 store per (mt,r)
        #pragma unroll
        for (int mt = 0; mt < 2; ++mt) {
          #pragma unroll
          for (int r = 0; r < 4; ++r) {
            const int m = mh * 32 + mt * 16 + q * 4 + r;
            unsigned pk = pkbf(fmaxf(acc[mt][0][r] + b1r[0], 0.f),
                               fmaxf(acc[mt][1][r] + b1r[1], 0.f));
            *(unsigned*)(hb + m * 512 + ((chp ^ (m & 15)) << 4) + ino) = pk;
          }
        }
      }
    }
    __syncthreads();   // bar2: feats reads done -> staging may overwrite

    // ---- (4) stage feats(i+1) from pre-issued gathers ----
    if (stg) {
      char* const bufn = (char*)feats;
      uintx4 pv;
      int m = mrow;
      #pragma unroll
      for (int tt = 0; tt < 4; ++tt) pv[tt] = bfmul2(ra0[tt], rb0[tt]);
      *(uintx4*)(bufn + m * 512 + ((c ^ (m & 15)) << 4)) = pv;
      m = mrow + 16;
      #pragma unroll
      for (int tt = 0; tt < 4; ++tt) pv[tt] = bfmul2(ra1[tt], rb1[tt]);
      *(uintx4*)(bufn + m * 512 + ((c ^ (m & 15)) << 4)) = pv;
      m = mrow + 32;
      #pragma unroll
      for (int tt = 0; tt < 4; ++tt) pv[tt] = bfmul2(ra2[tt], rb2[tt]);
      *(uintx4*)(bufn + m * 512 + ((c ^ (m & 15)) << 4)) = pv;
      m = mrow + 48;
      #pragma unroll
      for (int tt = 0; tt < 4; ++tt) pv[tt] = bfmul2(ra3[tt], rb3[tt]);
      *(uintx4*)(bufn + m * 512 + ((c ^ (m & 15)) << 4)) = pv;
    }
    __syncthreads();   // bar3: feats(i+1) ready; h1(i) ready for GEMM2 next iter
  }
}

extern "C" void kernel_launch(void* const* d_in, const int* in_sizes, int n_in,
                              void* d_out, int out_size, void* d_ws, size_t ws_size,
                              hipStream_t stream) {
  const float* x  = (const float*)d_in[0];
  const float* W1 = (const float*)d_in[1];
  const float* b1 = (const float*)d_in[2];
  const float* W2 = (const float*)d_in[3];
  const float* b2 = (const float*)d_in[4];
  const float* W3 = (const float*)d_in[5];
  const float* b3 = (const float*)d_in[6];
  // d_in[7] = edge_index (unused by the reference computation)
  const int*   ep = (const int*)d_in[8];
  float* out = (float*)d_out;

  const int NX = in_sizes[0];        // 100000*256 = 25,600,000
  const int E  = in_sizes[8] / 2;    // 1,000,000

  // workspace layout: xb (NX bf16) | w1t (256*256 bf16) | w2t (128*256 bf16)
  unsigned short* xb  = (unsigned short*)d_ws;
  unsigned short* w1t = (unsigned short*)((char*)d_ws + (size_t)NX * 2);
  unsigned short* w2t = w1t + 256 * 256;

  const int n4 = NX / 4;
  const int prep_threads = n4 + 256 * 256 + 128 * 256;
  prep_kernel<<<(prep_threads + 255) / 256, 256, 0, stream>>>(x, W1, W2, xb, w1t, w2t, n4);
  mlp_kernel<<<NBLOCKS, NTHREADS, 0, stream>>>(xb, w1t, w2t, b1, b2, W3, b3, ep, out, E);
}